// Round 14
// baseline (110.379 us; speedup 1.0000x reference)
//
#include <hip/hip_runtime.h>
#include <math.h>

#define HW 16384
#define C_DIM 256
#define V_DIM 6
#define PT 64
#define BK 32
#define KROW 40            // ushorts per pixel-row (80 B): b128 ops at bank floor
#define KT (PT * KROW)     // ushorts per K-tile in LDS

typedef short bf16x8 __attribute__((ext_vector_type(8)));
typedef float f32x4 __attribute__((ext_vector_type(4)));

// fp32 -> bf16 hi/lo split (truncation). |x - (hi+lo)| <= 2^-16 |x|.
__device__ __forceinline__ void split2(float x, unsigned short& h,
                                       unsigned short& l) {
    unsigned u = __float_as_uint(x);
    h = (unsigned short)(u >> 16);
    float xl = x - __uint_as_float(u & 0xFFFF0000u);
    l = (unsigned short)(__float_as_uint(xl) >> 16);
}

// ---------------------------------------------------------------------------
// K1: M = Wq^T @ Wk, stored as bf16 hi/lo.
// ---------------------------------------------------------------------------
__global__ void compute_M_kernel(const float* __restrict__ Wq,
                                 const float* __restrict__ Wk,
                                 unsigned short* __restrict__ Mh,
                                 unsigned short* __restrict__ Ml) {
    const int i = blockIdx.x;
    const int j = threadIdx.x;
    float a0 = 0.f, a1 = 0.f, a2 = 0.f, a3 = 0.f;
    #pragma unroll 4
    for (int o = 0; o < C_DIM; o += 4) {
        a0 = fmaf(Wq[(o + 0) * C_DIM + i], Wk[(o + 0) * C_DIM + j], a0);
        a1 = fmaf(Wq[(o + 1) * C_DIM + i], Wk[(o + 1) * C_DIM + j], a1);
        a2 = fmaf(Wq[(o + 2) * C_DIM + i], Wk[(o + 2) * C_DIM + j], a2);
        a3 = fmaf(Wq[(o + 3) * C_DIM + i], Wk[(o + 3) * C_DIM + j], a3);
    }
    float acc = (a0 + a1) + (a2 + a3);
    unsigned short h, l;
    split2(acc, h, l);
    Mh[i * C_DIM + j] = h;
    Ml[i * C_DIM + j] = l;
}

// ---------------------------------------------------------------------------
// K2 v14: FIFO-correct view pipeline.
// vmcnt is IN-ORDER (waits for the oldest outstanding loads): r13's ks-loop
// consumed A-fragments -- the NEWEST loads -- so every MFMA waitcnt drained
// the entire q/k prefetch burst. Fix:
//   * A panel (32 b128 from L2) loaded ONCE and PINNED via opaque asm
//     identities (compiler cannot sink/rematerialize, unlike r12);
//   * main loop consumes ONLY pinned registers + LDS;
//   * per view, consume order == issue order: split eats kreg (oldest),
//     then qx issued, then kreg(v+1) issued; epilogue eats qx leaving
//     kreg(v+1) in flight across the view boundary.
// 256 blocks (1/CU), 512 thr = 8 waves, wave owns 32 i-rows, LDS 80 KB.
// ---------------------------------------------------------------------------
__global__ __launch_bounds__(512, 2) void score_kernel(
        const float* __restrict__ q, const float* __restrict__ k,
        const unsigned short* __restrict__ Mh,
        const unsigned short* __restrict__ Ml,
        float* __restrict__ score) {
    const int tid  = threadIdx.x;
    const int lane = tid & 63;          // staging pixel
    const int w    = tid >> 6;          // wave 0..7; staging ch-group (4 ch)
    const int gp0  = blockIdx.x * PT;
    const int l15  = lane & 15;
    const int l4   = lane >> 4;

    __shared__ __align__(16) unsigned short Kh_s[8 * KT];   // 40 KB
    __shared__ __align__(16) unsigned short Kl_s[8 * KT];   // 40 KB

    const int ibase = w * 32;

    // ---- (1) A panel: issue all 32 b128 loads (L2-resident M) ----
    bf16x8 Ah[8][2], Al[8][2];
    #pragma unroll
    for (int ks = 0; ks < 8; ++ks)
        #pragma unroll
        for (int it = 0; it < 2; ++it) {
            int row = ibase + it * 16 + l15;
            Ah[ks][it] = *(const bf16x8*)(Mh + (size_t)row * C_DIM +
                                          ks * BK + l4 * 8);
            Al[ks][it] = *(const bf16x8*)(Ml + (size_t)row * C_DIM +
                                          ks * BK + l4 * 8);
        }

    // ---- (2) issue k(view 0) loads (newer than A) ----
    float kreg[8][4];
    {
        const float* kv = k + gp0;
        #pragma unroll
        for (int t = 0; t < 8; ++t) {
            const float* kp = kv + (size_t)(t * BK + w * 4) * HW + lane;
            #pragma unroll
            for (int e = 0; e < 4; ++e) kreg[t][e] = kp[(size_t)e * HW];
        }
    }

    // ---- (3) PIN the A panel: opaque asm identity forces residency; the
    //      implied wait (A older than kreg) leaves kreg in flight ----
    #pragma unroll
    for (int ks = 0; ks < 8; ++ks)
        #pragma unroll
        for (int it = 0; it < 2; ++it) {
            asm volatile("" : "+v"(Ah[ks][it]));
            asm volatile("" : "+v"(Al[ks][it]));
        }

    for (int v = 0; v < V_DIM; ++v) {
        const float* qv = q + (size_t)v * C_DIM * HW + gp0;

        if (v > 0) __syncthreads();   // s_red readers done; LDS reusable

        // ---- split kreg (OLDEST outstanding loads: FIFO) -> LDS image ----
        #pragma unroll
        for (int t = 0; t < 8; ++t) {
            unsigned short h[4], l[4];
            #pragma unroll
            for (int e = 0; e < 4; ++e) split2(kreg[t][e], h[e], l[e]);
            uint2 H, L;
            H.x = (unsigned)h[0] | ((unsigned)h[1] << 16);
            H.y = (unsigned)h[2] | ((unsigned)h[3] << 16);
            L.x = (unsigned)l[0] | ((unsigned)l[1] << 16);
            L.y = (unsigned)l[2] | ((unsigned)l[3] << 16);
            *(uint2*)&Kh_s[t * KT + lane * KROW + w * 4] = H;
            *(uint2*)&Kl_s[t * KT + lane * KROW + w * 4] = L;
        }
        __syncthreads();   // image ready

        // ---- issue qx(v), then kreg(v+1): same order they are consumed ----
        float qx[32];
        #pragma unroll
        for (int jt = 0; jt < 4; ++jt)
            #pragma unroll
            for (int it = 0; it < 2; ++it) {
                int irow = ibase + it * 16 + l4 * 4;
                const float* qp = qv + (size_t)irow * HW + jt * 16 + l15;
                #pragma unroll
                for (int r = 0; r < 4; ++r)
                    qx[jt * 8 + it * 4 + r] = qp[(size_t)r * HW];
            }
        if (v < V_DIM - 1) {
            const float* kv = k + (size_t)(v + 1) * C_DIM * HW + gp0;
            #pragma unroll
            for (int t = 0; t < 8; ++t) {
                const float* kp = kv + (size_t)(t * BK + w * 4) * HW + lane;
                #pragma unroll
                for (int e = 0; e < 4; ++e) kreg[t][e] = kp[(size_t)e * HW];
            }
        }

        // ---- ks-loop: pinned regs + LDS only; NO vm consumption ----
        f32x4 acc[2][4];
        #pragma unroll
        for (int a = 0; a < 2; ++a)
            #pragma unroll
            for (int b = 0; b < 4; ++b)
                acc[a][b] = (f32x4){0.f, 0.f, 0.f, 0.f};

        #pragma unroll
        for (int ks = 0; ks < 8; ++ks) {
            bf16x8 Bh[4];
            #pragma unroll
            for (int jt = 0; jt < 4; ++jt) {
                int bp = jt * 16 + l15;
                Bh[jt] = *(const bf16x8*)&Kh_s[ks * KT + bp * KROW + l4 * 8];
            }
            #pragma unroll
            for (int it = 0; it < 2; ++it)
                #pragma unroll
                for (int jt = 0; jt < 4; ++jt)
                    acc[it][jt] = __builtin_amdgcn_mfma_f32_16x16x32_bf16(
                                      Ah[ks][it], Bh[jt], acc[it][jt], 0, 0, 0);
            #pragma unroll
            for (int it = 0; it < 2; ++it)
                #pragma unroll
                for (int jt = 0; jt < 4; ++jt)
                    acc[it][jt] = __builtin_amdgcn_mfma_f32_16x16x32_bf16(
                                      Al[ks][it], Bh[jt], acc[it][jt], 0, 0, 0);
            bf16x8 Bl[4];
            #pragma unroll
            for (int jt = 0; jt < 4; ++jt) {
                int bp = jt * 16 + l15;
                Bl[jt] = *(const bf16x8*)&Kl_s[ks * KT + bp * KROW + l4 * 8];
            }
            #pragma unroll
            for (int it = 0; it < 2; ++it)
                #pragma unroll
                for (int jt = 0; jt < 4; ++jt)
                    acc[it][jt] = __builtin_amdgcn_mfma_f32_16x16x32_bf16(
                                      Ah[ks][it], Bl[jt], acc[it][jt], 0, 0, 0);
        }

        // ---- epilogue: consume qx (leaves kreg(v+1) outstanding) ----
        float sp[4];
        #pragma unroll
        for (int jt = 0; jt < 4; ++jt) sp[jt] = 0.f;
        #pragma unroll
        for (int jt = 0; jt < 4; ++jt) {
            #pragma unroll
            for (int it = 0; it < 2; ++it)
                #pragma unroll
                for (int r = 0; r < 4; ++r)
                    sp[jt] = fmaf(qx[jt * 8 + it * 4 + r],
                                  acc[it][jt][r], sp[jt]);
            sp[jt] += __shfl_xor(sp[jt], 16, 64);
            sp[jt] += __shfl_xor(sp[jt], 32, 64);
        }

        __syncthreads();   // all B-reads done -> Kh_s reusable as scratch
        float* s_red = (float*)Kh_s;    // [8][PT]
        if (lane < 16) {
            #pragma unroll
            for (int jt = 0; jt < 4; ++jt)
                s_red[w * PT + jt * 16 + lane] = sp[jt];
        }
        __syncthreads();
        if (tid < PT) {
            float s = 0.f;
            #pragma unroll
            for (int ww = 0; ww < 8; ++ww) s += s_red[ww * PT + tid];
            score[v * HW + gp0 + tid] = s;
        }
    }
}

// ---------------------------------------------------------------------------
// K4: split Wv into bf16 hi/lo (reuses the Mh/Ml workspace).
// ---------------------------------------------------------------------------
__global__ void wsplit_kernel(const float* __restrict__ Wv,
                              unsigned short* __restrict__ Wvh,
                              unsigned short* __restrict__ Wvl) {
    const int i = blockIdx.x;
    const int j = threadIdx.x;
    unsigned short h, l;
    split2(Wv[i * C_DIM + j], h, l);
    Wvh[i * C_DIM + j] = h;
    Wvl[i * C_DIM + j] = l;
}

// ---------------------------------------------------------------------------
// K5 (unchanged): out = Wv @ vbar with inline softmax.  ~21 us vs ~19 floor.
// ---------------------------------------------------------------------------
__global__ __launch_bounds__(512, 2) void out_gemm_kernel(
        const float* __restrict__ vin,
        const unsigned short* __restrict__ Wvh,
        const unsigned short* __restrict__ Wvl,
        const float* __restrict__ score,
        float* __restrict__ out) {
    const int tid  = threadIdx.x;
    const int lane = tid & 63;
    const int w    = tid >> 6;          // 0..7
    const int gp0  = blockIdx.x * PT;
    const int l15  = lane & 15;
    const int l4   = lane >> 4;
    const int jg   = w;                 // staging channel group (4 ch)

    __shared__ __align__(16) unsigned short Xh_s[2][KT];
    __shared__ __align__(16) unsigned short Xl_s[2][KT];

    float wr[V_DIM];
    {
        float s[V_DIM];
        float mx = -1e30f;
        #pragma unroll
        for (int vv = 0; vv < V_DIM; ++vv) {
            s[vv] = score[vv * HW + gp0 + lane];
            mx = fmaxf(mx, s[vv]);
        }
        float sum = 0.f;
        #pragma unroll
        for (int vv = 0; vv < V_DIM; ++vv) {
            s[vv] = __expf(s[vv] - mx);
            sum += s[vv];
        }
        float inv = 1.0f / sum;
        #pragma unroll
        for (int vv = 0; vv < V_DIM; ++vv) wr[vv] = s[vv] * inv;
    }

    const float* vbase = vin + gp0 + lane;
    const int obase = w * 32;

    f32x4 acc[2][4];
    #pragma unroll
    for (int a = 0; a < 2; ++a)
        #pragma unroll
        for (int b = 0; b < 4; ++b)
            acc[a][b] = (f32x4){0.f, 0.f, 0.f, 0.f};

    float vx[2][4][V_DIM];
    bf16x8 Ah[2][2], Al[2][2];

    {
        float x0[4][V_DIM];
        #pragma unroll
        for (int vv = 0; vv < V_DIM; ++vv)
            #pragma unroll
            for (int e = 0; e < 4; ++e)
                x0[e][vv] = vbase[(size_t)(vv * C_DIM + jg * 4 + e) * HW];
        unsigned short h[4], l[4];
        #pragma unroll
        for (int e = 0; e < 4; ++e) {
            float s = 0.f;
            #pragma unroll
            for (int vv = 0; vv < V_DIM; ++vv) s = fmaf(wr[vv], x0[e][vv], s);
            split2(s, h[e], l[e]);
        }
        uint2 H, L;
        H.x = (unsigned)h[0] | ((unsigned)h[1] << 16);
        H.y = (unsigned)h[2] | ((unsigned)h[3] << 16);
        L.x = (unsigned)l[0] | ((unsigned)l[1] << 16);
        L.y = (unsigned)l[2] | ((unsigned)l[3] << 16);
        *(uint2*)&Xh_s[0][lane * KROW + jg * 4] = H;
        *(uint2*)&Xl_s[0][lane * KROW + jg * 4] = L;

        #pragma unroll
        for (int vv = 0; vv < V_DIM; ++vv)
            #pragma unroll
            for (int e = 0; e < 4; ++e)
                vx[1][e][vv] = vbase[(size_t)(vv * C_DIM + BK + jg * 4 + e) * HW];

        #pragma unroll
        for (int it = 0; it < 2; ++it) {
            int row = obase + it * 16 + l15;
            Ah[0][it] = *(const bf16x8*)(Wvh + (size_t)row * C_DIM + l4 * 8);
            Al[0][it] = *(const bf16x8*)(Wvl + (size_t)row * C_DIM + l4 * 8);
        }
    }
    __syncthreads();

    #pragma unroll
    for (int ks = 0; ks < 8; ++ks) {
        const int cur = ks & 1;

        if (ks < 7) {
            #pragma unroll
            for (int it = 0; it < 2; ++it) {
                int row = obase + it * 16 + l15;
                Ah[cur ^ 1][it] = *(const bf16x8*)(Wvh + (size_t)row * C_DIM +
                                                   (ks + 1) * BK + l4 * 8);
                Al[cur ^ 1][it] = *(const bf16x8*)(Wvl + (size_t)row * C_DIM +
                                                   (ks + 1) * BK + l4 * 8);
            }
        }
        if (ks < 6) {
            #pragma unroll
            for (int vv = 0; vv < V_DIM; ++vv)
                #pragma unroll
                for (int e = 0; e < 4; ++e)
                    vx[cur][e][vv] = vbase[(size_t)(vv * C_DIM + (ks + 2) * BK +
                                                    jg * 4 + e) * HW];
        }

        bf16x8 Bh[4], Bl[4];
        #pragma unroll
        for (int jt = 0; jt < 4; ++jt) {
            int bp = jt * 16 + l15;
            Bh[jt] = *(const bf16x8*)&Xh_s[cur][bp * KROW + l4 * 8];
            Bl[jt] = *(const bf16x8*)&Xl_s[cur][bp * KROW + l4 * 8];
        }
        #pragma unroll
        for (int it = 0; it < 2; ++it)
            #pragma unroll
            for (int jt = 0; jt < 4; ++jt)
                acc[it][jt] = __builtin_amdgcn_mfma_f32_16x16x32_bf16(
                                  Ah[cur][it], Bh[jt], acc[it][jt], 0, 0, 0);
        #pragma unroll
        for (int it = 0; it < 2; ++it)
            #pragma unroll
            for (int jt = 0; jt < 4; ++jt)
                acc[it][jt] = __builtin_amdgcn_mfma_f32_16x16x32_bf16(
                                  Ah[cur][it], Bl[jt], acc[it][jt], 0, 0, 0);
        #pragma unroll
        for (int it = 0; it < 2; ++it)
            #pragma unroll
            for (int jt = 0; jt < 4; ++jt)
                acc[it][jt] = __builtin_amdgcn_mfma_f32_16x16x32_bf16(
                                  Al[cur][it], Bh[jt], acc[it][jt], 0, 0, 0);

        if (ks < 7) {
            unsigned short h[4], l[4];
            #pragma unroll
            for (int e = 0; e < 4; ++e) {
                float s = 0.f;
                #pragma unroll
                for (int vv = 0; vv < V_DIM; ++vv)
                    s = fmaf(wr[vv], vx[cur ^ 1][e][vv], s);
                split2(s, h[e], l[e]);
            }
            uint2 H, L;
            H.x = (unsigned)h[0] | ((unsigned)h[1] << 16);
            H.y = (unsigned)h[2] | ((unsigned)h[3] << 16);
            L.x = (unsigned)l[0] | ((unsigned)l[1] << 16);
            L.y = (unsigned)l[2] | ((unsigned)l[3] << 16);
            *(uint2*)&Xh_s[cur ^ 1][lane * KROW + jg * 4] = H;
            *(uint2*)&Xl_s[cur ^ 1][lane * KROW + jg * 4] = L;
        }
        __syncthreads();
    }

    #pragma unroll
    for (int it = 0; it < 2; ++it)
        #pragma unroll
        for (int jt = 0; jt < 4; ++jt)
            #pragma unroll
            for (int r = 0; r < 4; ++r) {
                int o = obase + it * 16 + l4 * 4 + r;
                out[(size_t)o * HW + gp0 + jt * 16 + l15] = acc[it][jt][r];
            }
}

// ---------------------------------------------------------------------------
extern "C" void kernel_launch(void* const* d_in, const int* in_sizes, int n_in,
                              void* d_out, int out_size, void* d_ws, size_t ws_size,
                              hipStream_t stream) {
    const float* q  = (const float*)d_in[0];
    const float* k  = (const float*)d_in[1];
    const float* v  = (const float*)d_in[2];
    const float* Wq = (const float*)d_in[3];
    const float* Wk = (const float*)d_in[4];
    const float* Wv = (const float*)d_in[5];
    float* out = (float*)d_out;

    unsigned short* Mh = (unsigned short*)d_ws;          // 128 KB (later: Wvh)
    unsigned short* Ml = Mh + C_DIM * C_DIM;             // 128 KB (later: Wvl)
    float* score = (float*)(Ml + C_DIM * C_DIM);         // 384 KB

    compute_M_kernel<<<C_DIM, C_DIM, 0, stream>>>(Wq, Wk, Mh, Ml);
    score_kernel<<<HW / PT, 512, 0, stream>>>(q, k, Mh, Ml, score);
    wsplit_kernel<<<C_DIM, C_DIM, 0, stream>>>(Wv, Mh, Ml);
    out_gemm_kernel<<<HW / PT, 512, 0, stream>>>(v, Mh, Ml, score, out);
}

// Round 15
// 105.818 us; speedup vs baseline: 1.0431x; 1.0431x over previous
//
#include <hip/hip_runtime.h>
#include <math.h>

#define HW 16384
#define C_DIM 256
#define V_DIM 6
#define PT 64
#define BK 32
#define KROW 40            // ushorts per pixel-row (80 B): b128 ops at bank floor
#define KT (PT * KROW)     // ushorts per K-tile in LDS

typedef short bf16x8 __attribute__((ext_vector_type(8)));
typedef float f32x4 __attribute__((ext_vector_type(4)));

// fp32 -> bf16 hi/lo split (truncation). |x - (hi+lo)| <= 2^-16 |x|.
__device__ __forceinline__ void split2(float x, unsigned short& h,
                                       unsigned short& l) {
    unsigned u = __float_as_uint(x);
    h = (unsigned short)(u >> 16);
    float xl = x - __uint_as_float(u & 0xFFFF0000u);
    l = (unsigned short)(__float_as_uint(xl) >> 16);
}

// ---------------------------------------------------------------------------
// K1: M = Wq^T @ Wk, stored as bf16 hi/lo.
// ---------------------------------------------------------------------------
__global__ void compute_M_kernel(const float* __restrict__ Wq,
                                 const float* __restrict__ Wk,
                                 unsigned short* __restrict__ Mh,
                                 unsigned short* __restrict__ Ml) {
    const int i = blockIdx.x;
    const int j = threadIdx.x;
    float a0 = 0.f, a1 = 0.f, a2 = 0.f, a3 = 0.f;
    #pragma unroll 4
    for (int o = 0; o < C_DIM; o += 4) {
        a0 = fmaf(Wq[(o + 0) * C_DIM + i], Wk[(o + 0) * C_DIM + j], a0);
        a1 = fmaf(Wq[(o + 1) * C_DIM + i], Wk[(o + 1) * C_DIM + j], a1);
        a2 = fmaf(Wq[(o + 2) * C_DIM + i], Wk[(o + 2) * C_DIM + j], a2);
        a3 = fmaf(Wq[(o + 3) * C_DIM + i], Wk[(o + 3) * C_DIM + j], a3);
    }
    float acc = (a0 + a1) + (a2 + a3);
    unsigned short h, l;
    split2(acc, h, l);
    Mh[i * C_DIM + j] = h;
    Ml[i * C_DIM + j] = l;
}

// ---------------------------------------------------------------------------
// K2 v15: out_gemm-CLONE shape.  out_gemm moves the same bytes with the same
// strides at ~8 B/cy/CU; score has been at ~4.  Its structural delta: small
// load packet EVERY iteration, consumed 1-2 iterations later (FIFO), plain
// __syncthreads; score bursted 64 loads/view (vmem-queue stall at issue,
// then silence).  This kernel is the clone: 48 flat iterations (6 views x 8
// K-tiles), dbuf 20 KB K-image, per iter {4 A-frag b128 (t+1, L2), 8 q loads
// (first 4 iters/view), 4 k loads (t+2)} -> MFMA(t) -> [epilogue @ks=7] ->
// split kreg(t+1) -> __syncthreads.  <=24 loads outstanding, memory always
// fed.  256 blocks, 512 thr = 8 waves, wave owns 32 i-rows.
// ---------------------------------------------------------------------------
__global__ __launch_bounds__(512, 2) void score_kernel(
        const float* __restrict__ q, const float* __restrict__ k,
        const unsigned short* __restrict__ Mh,
        const unsigned short* __restrict__ Ml,
        float* __restrict__ score) {
    const int tid  = threadIdx.x;
    const int lane = tid & 63;          // staging pixel
    const int w    = tid >> 6;          // wave 0..7; staging ch-group (4 ch)
    const int gp0  = blockIdx.x * PT;
    const int l15  = lane & 15;
    const int l4   = lane >> 4;

    __shared__ __align__(16) unsigned short Kh_s[2][KT];   // 10 KB
    __shared__ __align__(16) unsigned short Kl_s[2][KT];   // 10 KB
    __shared__ float s_red[8][PT];                         // 2 KB

    const int ibase = w * 32;

    f32x4 acc[2][4];
    #pragma unroll
    for (int a = 0; a < 2; ++a)
        #pragma unroll
        for (int b = 0; b < 4; ++b)
            acc[a][b] = (f32x4){0.f, 0.f, 0.f, 0.f};

    bf16x8 Ah[2][2], Al[2][2];   // A(t) in set [t&1] = [ks&1]
    float kreg[2][4];            // tile s in kreg[s&1]
    float qx[32];

    // ---- prologue: stage tile (0,0); kreg[1] = tile (0,1); A(0) ----
    {
        const float* kp = k + gp0 + (size_t)(w * 4) * HW + lane;
        float x[4];
        #pragma unroll
        for (int e = 0; e < 4; ++e) x[e] = kp[(size_t)e * HW];
        unsigned short h[4], l[4];
        #pragma unroll
        for (int e = 0; e < 4; ++e) split2(x[e], h[e], l[e]);
        uint2 H, L;
        H.x = (unsigned)h[0] | ((unsigned)h[1] << 16);
        H.y = (unsigned)h[2] | ((unsigned)h[3] << 16);
        L.x = (unsigned)l[0] | ((unsigned)l[1] << 16);
        L.y = (unsigned)l[2] | ((unsigned)l[3] << 16);
        *(uint2*)&Kh_s[0][lane * KROW + w * 4] = H;
        *(uint2*)&Kl_s[0][lane * KROW + w * 4] = L;

        const float* kp1 = k + gp0 + (size_t)(BK + w * 4) * HW + lane;
        #pragma unroll
        for (int e = 0; e < 4; ++e) kreg[1][e] = kp1[(size_t)e * HW];

        #pragma unroll
        for (int it = 0; it < 2; ++it) {
            int row = ibase + it * 16 + l15;
            Ah[0][it] = *(const bf16x8*)(Mh + (size_t)row * C_DIM + l4 * 8);
            Al[0][it] = *(const bf16x8*)(Ml + (size_t)row * C_DIM + l4 * 8);
        }
    }
    __syncthreads();

    for (int v = 0; v < V_DIM; ++v) {
        const float* qv = q + (size_t)v * C_DIM * HW + gp0;

        #pragma unroll
        for (int ks = 0; ks < 8; ++ks) {
            const int cur = ks & 1;          // == t&1, since v*8 is even
            const bool last_t  = (v == V_DIM - 1) && (ks == 7);
            const bool last_t2 = (v == V_DIM - 1) && (ks >= 6);

            // (1) A(t+1) fragments (L2; channel block ((ks+1)&7)*BK)
            if (!last_t) {
                const int kb = ((ks + 1) & 7) * BK;
                #pragma unroll
                for (int it = 0; it < 2; ++it) {
                    int row = ibase + it * 16 + l15;
                    Ah[cur ^ 1][it] = *(const bf16x8*)(Mh + (size_t)row * C_DIM +
                                                       kb + l4 * 8);
                    Al[cur ^ 1][it] = *(const bf16x8*)(Ml + (size_t)row * C_DIM +
                                                       kb + l4 * 8);
                }
            }
            // (2) q chunk: 8 loads per iter over first 4 iters of the view
            if (ks < 4) {
                const int jt = ks;
                #pragma unroll
                for (int it = 0; it < 2; ++it) {
                    int irow = ibase + it * 16 + l4 * 4;
                    const float* qp = qv + (size_t)irow * HW + jt * 16 + l15;
                    #pragma unroll
                    for (int r = 0; r < 4; ++r)
                        qx[jt * 8 + it * 4 + r] = qp[(size_t)r * HW];
                }
            }
            // (3) k chunk for tile t+2 -> kreg[cur]
            if (!last_t2) {
                const int v2  = (ks >= 6) ? v + 1 : v;
                const int kb2 = ((ks + 2) & 7) * BK;
                const float* kp = k + (size_t)v2 * C_DIM * HW + gp0 +
                                  (size_t)(kb2 + w * 4) * HW + lane;
                #pragma unroll
                for (int e = 0; e < 4; ++e) kreg[cur][e] = kp[(size_t)e * HW];
            }

            // (4) B from LDS buf[cur] + 24 MFMA (A(t): oldest outstanding)
            bf16x8 Bh[4];
            #pragma unroll
            for (int jt = 0; jt < 4; ++jt) {
                int bp = jt * 16 + l15;
                Bh[jt] = *(const bf16x8*)&Kh_s[cur][bp * KROW + l4 * 8];
            }
            #pragma unroll
            for (int it = 0; it < 2; ++it)
                #pragma unroll
                for (int jt = 0; jt < 4; ++jt)
                    acc[it][jt] = __builtin_amdgcn_mfma_f32_16x16x32_bf16(
                                      Ah[cur][it], Bh[jt], acc[it][jt], 0, 0, 0);
            #pragma unroll
            for (int it = 0; it < 2; ++it)
                #pragma unroll
                for (int jt = 0; jt < 4; ++jt)
                    acc[it][jt] = __builtin_amdgcn_mfma_f32_16x16x32_bf16(
                                      Al[cur][it], Bh[jt], acc[it][jt], 0, 0, 0);
            bf16x8 Bl[4];
            #pragma unroll
            for (int jt = 0; jt < 4; ++jt) {
                int bp = jt * 16 + l15;
                Bl[jt] = *(const bf16x8*)&Kl_s[cur][bp * KROW + l4 * 8];
            }
            #pragma unroll
            for (int it = 0; it < 2; ++it)
                #pragma unroll
                for (int jt = 0; jt < 4; ++jt)
                    acc[it][jt] = __builtin_amdgcn_mfma_f32_16x16x32_bf16(
                                      Ah[cur][it], Bl[jt], acc[it][jt], 0, 0, 0);

            // (5) view epilogue: consume qx (newest q is 4 iters old)
            if (ks == 7) {
                float sp[4];
                #pragma unroll
                for (int jt = 0; jt < 4; ++jt) sp[jt] = 0.f;
                #pragma unroll
                for (int jt = 0; jt < 4; ++jt) {
                    #pragma unroll
                    for (int it = 0; it < 2; ++it)
                        #pragma unroll
                        for (int r = 0; r < 4; ++r)
                            sp[jt] = fmaf(qx[jt * 8 + it * 4 + r],
                                          acc[it][jt][r], sp[jt]);
                    sp[jt] += __shfl_xor(sp[jt], 16, 64);
                    sp[jt] += __shfl_xor(sp[jt], 32, 64);
                }
                if (lane < 16) {
                    #pragma unroll
                    for (int jt = 0; jt < 4; ++jt)
                        s_red[w][jt * 16 + lane] = sp[jt];
                }
                __syncthreads();
                if (tid < PT) {
                    float s = 0.f;
                    #pragma unroll
                    for (int ww = 0; ww < 8; ++ww) s += s_red[ww][tid];
                    score[v * HW + gp0 + tid] = s;
                }
                #pragma unroll
                for (int a = 0; a < 2; ++a)
                    #pragma unroll
                    for (int b = 0; b < 4; ++b)
                        acc[a][b] = (f32x4){0.f, 0.f, 0.f, 0.f};
            }

            // (6) stage tile t+1: split kreg[cur^1] (loaded last iter)
            if (!last_t) {
                unsigned short h[4], l[4];
                #pragma unroll
                for (int e = 0; e < 4; ++e) split2(kreg[cur ^ 1][e], h[e], l[e]);
                uint2 H, L;
                H.x = (unsigned)h[0] | ((unsigned)h[1] << 16);
                H.y = (unsigned)h[2] | ((unsigned)h[3] << 16);
                L.x = (unsigned)l[0] | ((unsigned)l[1] << 16);
                L.y = (unsigned)l[2] | ((unsigned)l[3] << 16);
                *(uint2*)&Kh_s[cur ^ 1][lane * KROW + w * 4] = H;
                *(uint2*)&Kl_s[cur ^ 1][lane * KROW + w * 4] = L;
            }
            __syncthreads();
        }
    }
}

// ---------------------------------------------------------------------------
// K4: split Wv into bf16 hi/lo (reuses the Mh/Ml workspace).
// ---------------------------------------------------------------------------
__global__ void wsplit_kernel(const float* __restrict__ Wv,
                              unsigned short* __restrict__ Wvh,
                              unsigned short* __restrict__ Wvl) {
    const int i = blockIdx.x;
    const int j = threadIdx.x;
    unsigned short h, l;
    split2(Wv[i * C_DIM + j], h, l);
    Wvh[i * C_DIM + j] = h;
    Wvl[i * C_DIM + j] = l;
}

// ---------------------------------------------------------------------------
// K5 (unchanged): out = Wv @ vbar with inline softmax.  ~21 us vs ~19 floor.
// ---------------------------------------------------------------------------
__global__ __launch_bounds__(512, 2) void out_gemm_kernel(
        const float* __restrict__ vin,
        const unsigned short* __restrict__ Wvh,
        const unsigned short* __restrict__ Wvl,
        const float* __restrict__ score,
        float* __restrict__ out) {
    const int tid  = threadIdx.x;
    const int lane = tid & 63;
    const int w    = tid >> 6;          // 0..7
    const int gp0  = blockIdx.x * PT;
    const int l15  = lane & 15;
    const int l4   = lane >> 4;
    const int jg   = w;                 // staging channel group (4 ch)

    __shared__ __align__(16) unsigned short Xh_s[2][KT];
    __shared__ __align__(16) unsigned short Xl_s[2][KT];

    float wr[V_DIM];
    {
        float s[V_DIM];
        float mx = -1e30f;
        #pragma unroll
        for (int vv = 0; vv < V_DIM; ++vv) {
            s[vv] = score[vv * HW + gp0 + lane];
            mx = fmaxf(mx, s[vv]);
        }
        float sum = 0.f;
        #pragma unroll
        for (int vv = 0; vv < V_DIM; ++vv) {
            s[vv] = __expf(s[vv] - mx);
            sum += s[vv];
        }
        float inv = 1.0f / sum;
        #pragma unroll
        for (int vv = 0; vv < V_DIM; ++vv) wr[vv] = s[vv] * inv;
    }

    const float* vbase = vin + gp0 + lane;
    const int obase = w * 32;

    f32x4 acc[2][4];
    #pragma unroll
    for (int a = 0; a < 2; ++a)
        #pragma unroll
        for (int b = 0; b < 4; ++b)
            acc[a][b] = (f32x4){0.f, 0.f, 0.f, 0.f};

    float vx[2][4][V_DIM];
    bf16x8 Ah[2][2], Al[2][2];

    {
        float x0[4][V_DIM];
        #pragma unroll
        for (int vv = 0; vv < V_DIM; ++vv)
            #pragma unroll
            for (int e = 0; e < 4; ++e)
                x0[e][vv] = vbase[(size_t)(vv * C_DIM + jg * 4 + e) * HW];
        unsigned short h[4], l[4];
        #pragma unroll
        for (int e = 0; e < 4; ++e) {
            float s = 0.f;
            #pragma unroll
            for (int vv = 0; vv < V_DIM; ++vv) s = fmaf(wr[vv], x0[e][vv], s);
            split2(s, h[e], l[e]);
        }
        uint2 H, L;
        H.x = (unsigned)h[0] | ((unsigned)h[1] << 16);
        H.y = (unsigned)h[2] | ((unsigned)h[3] << 16);
        L.x = (unsigned)l[0] | ((unsigned)l[1] << 16);
        L.y = (unsigned)l[2] | ((unsigned)l[3] << 16);
        *(uint2*)&Xh_s[0][lane * KROW + jg * 4] = H;
        *(uint2*)&Xl_s[0][lane * KROW + jg * 4] = L;

        #pragma unroll
        for (int vv = 0; vv < V_DIM; ++vv)
            #pragma unroll
            for (int e = 0; e < 4; ++e)
                vx[1][e][vv] = vbase[(size_t)(vv * C_DIM + BK + jg * 4 + e) * HW];

        #pragma unroll
        for (int it = 0; it < 2; ++it) {
            int row = obase + it * 16 + l15;
            Ah[0][it] = *(const bf16x8*)(Wvh + (size_t)row * C_DIM + l4 * 8);
            Al[0][it] = *(const bf16x8*)(Wvl + (size_t)row * C_DIM + l4 * 8);
        }
    }
    __syncthreads();

    #pragma unroll
    for (int ks = 0; ks < 8; ++ks) {
        const int cur = ks & 1;

        if (ks < 7) {
            #pragma unroll
            for (int it = 0; it < 2; ++it) {
                int row = obase + it * 16 + l15;
                Ah[cur ^ 1][it] = *(const bf16x8*)(Wvh + (size_t)row * C_DIM +
                                                   (ks + 1) * BK + l4 * 8);
                Al[cur ^ 1][it] = *(const bf16x8*)(Wvl + (size_t)row * C_DIM +
                                                   (ks + 1) * BK + l4 * 8);
            }
        }
        if (ks < 6) {
            #pragma unroll
            for (int vv = 0; vv < V_DIM; ++vv)
                #pragma unroll
                for (int e = 0; e < 4; ++e)
                    vx[cur][e][vv] = vbase[(size_t)(vv * C_DIM + (ks + 2) * BK +
                                                    jg * 4 + e) * HW];
        }

        bf16x8 Bh[4], Bl[4];
        #pragma unroll
        for (int jt = 0; jt < 4; ++jt) {
            int bp = jt * 16 + l15;
            Bh[jt] = *(const bf16x8*)&Xh_s[cur][bp * KROW + l4 * 8];
            Bl[jt] = *(const bf16x8*)&Xl_s[cur][bp * KROW + l4 * 8];
        }
        #pragma unroll
        for (int it = 0; it < 2; ++it)
            #pragma unroll
            for (int jt = 0; jt < 4; ++jt)
                acc[it][jt] = __builtin_amdgcn_mfma_f32_16x16x32_bf16(
                                  Ah[cur][it], Bh[jt], acc[it][jt], 0, 0, 0);
        #pragma unroll
        for (int it = 0; it < 2; ++it)
            #pragma unroll
            for (int jt = 0; jt < 4; ++jt)
                acc[it][jt] = __builtin_amdgcn_mfma_f32_16x16x32_bf16(
                                  Ah[cur][it], Bl[jt], acc[it][jt], 0, 0, 0);
        #pragma unroll
        for (int it = 0; it < 2; ++it)
            #pragma unroll
            for (int jt = 0; jt < 4; ++jt)
                acc[it][jt] = __builtin_amdgcn_mfma_f32_16x16x32_bf16(
                                  Al[cur][it], Bh[jt], acc[it][jt], 0, 0, 0);

        if (ks < 7) {
            unsigned short h[4], l[4];
            #pragma unroll
            for (int e = 0; e < 4; ++e) {
                float s = 0.f;
                #pragma unroll
                for (int vv = 0; vv < V_DIM; ++vv)
                    s = fmaf(wr[vv], vx[cur ^ 1][e][vv], s);
                split2(s, h[e], l[e]);
            }
            uint2 H, L;
            H.x = (unsigned)h[0] | ((unsigned)h[1] << 16);
            H.y = (unsigned)h[2] | ((unsigned)h[3] << 16);
            L.x = (unsigned)l[0] | ((unsigned)l[1] << 16);
            L.y = (unsigned)l[2] | ((unsigned)l[3] << 16);
            *(uint2*)&Xh_s[cur ^ 1][lane * KROW + jg * 4] = H;
            *(uint2*)&Xl_s[cur ^ 1][lane * KROW + jg * 4] = L;
        }
        __syncthreads();
    }

    #pragma unroll
    for (int it = 0; it < 2; ++it)
        #pragma unroll
        for (int jt = 0; jt < 4; ++jt)
            #pragma unroll
            for (int r = 0; r < 4; ++r) {
                int o = obase + it * 16 + l4 * 4 + r;
                out[(size_t)o * HW + gp0 + jt * 16 + l15] = acc[it][jt][r];
            }
}

// ---------------------------------------------------------------------------
extern "C" void kernel_launch(void* const* d_in, const int* in_sizes, int n_in,
                              void* d_out, int out_size, void* d_ws, size_t ws_size,
                              hipStream_t stream) {
    const float* q  = (const float*)d_in[0];
    const float* k  = (const float*)d_in[1];
    const float* v  = (const float*)d_in[2];
    const float* Wq = (const float*)d_in[3];
    const float* Wk = (const float*)d_in[4];
    const float* Wv = (const float*)d_in[5];
    float* out = (float*)d_out;

    unsigned short* Mh = (unsigned short*)d_ws;          // 128 KB (later: Wvh)
    unsigned short* Ml = Mh + C_DIM * C_DIM;             // 128 KB (later: Wvl)
    float* score = (float*)(Ml + C_DIM * C_DIM);         // 384 KB

    compute_M_kernel<<<C_DIM, C_DIM, 0, stream>>>(Wq, Wk, Mh, Ml);
    score_kernel<<<HW / PT, 512, 0, stream>>>(q, k, Mh, Ml, score);
    wsplit_kernel<<<C_DIM, C_DIM, 0, stream>>>(Wv, Mh, Ml);
    out_gemm_kernel<<<HW / PT, 512, 0, stream>>>(v, Mh, Ml, score, out);
}